// Round 2
// baseline (843.849 us; speedup 1.0000x reference)
//
#include <hip/hip_runtime.h>

#define B_ 32
#define N_ 4
#define D_ 128
#define HW_ 1024
#define M_ 32768
#define K_ 1024

#define IDX_OFF 16777216
#define LOSS_OFF 16908288
#define PERP_OFF 16908292

// ws float layout
#define WS_LOSS 0        // 4 floats (per-layer loss accum)
#define WS_CNT 1024      // 4*1024 floats (histogram)
#define WS_ENORM 8192    // 4*1024 floats (0.5*||e||^2)
#define WS_ETS 16384     // 4*128*1024 floats (d-major codebook)

#define MARGIN 0.03f     // fp32 score gap below which we re-check in fp64

// --- prep: transpose codebook to d-major + 0.5*||e||^2 ---
__global__ void vq_prep(const float* __restrict__ cb, float* __restrict__ ws) {
  int t = blockIdx.x * 256 + threadIdx.x;  // 0..4095
  int n = t >> 10, k = t & 1023;
  const float* row = cb + (size_t)(n * K_ + k) * D_;
  float* Ets = ws + WS_ETS + n * (D_ * K_);
  float ss = 0.f;
#pragma unroll 4
  for (int d = 0; d < D_; ++d) {
    float v = row[d];
    ss = fmaf(v, v, ss);
    Ets[d * K_ + k] = v;  // coalesced store (k contiguous across lanes)
  }
  ws[WS_ENORM + t] = 0.5f * ss;
}

// --- main: fused score GEMM + argmin(+fp64 tie refine) + q gather + loss ---
__global__ __launch_bounds__(256) void vq_main(const float* __restrict__ x,
                                               const float* __restrict__ cb,
                                               float* __restrict__ ws,
                                               float* __restrict__ out) {
  __shared__ float Xt[128 * 64];  // [d][m], 32KB
  __shared__ float Et[128 * 64];  // [d][k], 32KB; reused for reductions
  const int tid = threadIdx.x;
  const int bid = blockIdx.x;
  const int n = bid >> 9;          // 512 m-blocks per layer
  const int mblk = bid & 511;
  const int b = mblk >> 4;         // 16 blocks per image (HW=1024, TM=64)
  const int hw0 = (mblk & 15) << 6;

  const float* xbase = x + (size_t)((b * 4 + n) * 128) * 1024 + hw0;
  const float* cbn = cb + (size_t)n * K_ * D_;
  float4* Xt4 = (float4*)Xt;
  float4* Et4 = (float4*)Et;

  // load X tile [128 d][64 m]
#pragma unroll
  for (int it = 0; it < 8; ++it) {
    int l = it * 256 + tid;
    int d = l >> 4, mv = l & 15;
    Xt4[l] = *(const float4*)(xbase + d * 1024 + mv * 4);
  }

  const float* EtsBase = ws + WS_ETS + n * (D_ * K_);
  const float* enorm = ws + WS_ENORM + n * K_;
  const int tk = tid & 15, tm = tid >> 4;

  float bestS[4], best2[4];
  int bestI[4];
#pragma unroll
  for (int i = 0; i < 4; ++i) { bestS[i] = -3.4e38f; best2[i] = -3.4e38f; bestI[i] = 0; }

  for (int kt = 0; kt < 16; ++kt) {
    const int k0 = kt * 64;
    __syncthreads();
    // load E tile [128 d][64 k] from pre-transposed d-major buffer
#pragma unroll
    for (int it = 0; it < 8; ++it) {
      int l = it * 256 + tid;
      int d = l >> 4, kv = l & 15;
      Et4[l] = *(const float4*)(EtsBase + d * 1024 + k0 + kv * 4);
    }
    float4 en = *(const float4*)(enorm + k0 + tk * 4);
    __syncthreads();

    float acc[4][4];
#pragma unroll
    for (int i = 0; i < 4; ++i)
#pragma unroll
      for (int j = 0; j < 4; ++j) acc[i][j] = 0.f;

    const float4* Xr = Xt4 + tm;  // row stride 16 float4
    const float4* Er = Et4 + tk;
#pragma unroll 4
    for (int d = 0; d < 128; ++d) {
      float4 xv = Xr[d * 16];
      float4 ev = Er[d * 16];
      acc[0][0] = fmaf(xv.x, ev.x, acc[0][0]);
      acc[0][1] = fmaf(xv.x, ev.y, acc[0][1]);
      acc[0][2] = fmaf(xv.x, ev.z, acc[0][2]);
      acc[0][3] = fmaf(xv.x, ev.w, acc[0][3]);
      acc[1][0] = fmaf(xv.y, ev.x, acc[1][0]);
      acc[1][1] = fmaf(xv.y, ev.y, acc[1][1]);
      acc[1][2] = fmaf(xv.y, ev.z, acc[1][2]);
      acc[1][3] = fmaf(xv.y, ev.w, acc[1][3]);
      acc[2][0] = fmaf(xv.z, ev.x, acc[2][0]);
      acc[2][1] = fmaf(xv.z, ev.y, acc[2][1]);
      acc[2][2] = fmaf(xv.z, ev.z, acc[2][2]);
      acc[2][3] = fmaf(xv.z, ev.w, acc[2][3]);
      acc[3][0] = fmaf(xv.w, ev.x, acc[3][0]);
      acc[3][1] = fmaf(xv.w, ev.y, acc[3][1]);
      acc[3][2] = fmaf(xv.w, ev.z, acc[3][2]);
      acc[3][3] = fmaf(xv.w, ev.w, acc[3][3]);
    }
    // fused top-2 epilogue: score = x.e - 0.5||e||^2 ; k ascending (strict >)
    float enj[4] = {en.x, en.y, en.z, en.w};
#pragma unroll
    for (int i = 0; i < 4; ++i) {
#pragma unroll
      for (int j = 0; j < 4; ++j) {
        float s = acc[i][j] - enj[j];
        if (s > bestS[i]) {
          best2[i] = bestS[i];
          bestS[i] = s;
          bestI[i] = k0 + tk * 4 + j;
        } else if (s > best2[i]) {
          best2[i] = s;
        }
      }
    }
  }

  // cross-thread reduce over the 16 tk threads per m-row (alias Et)
  __syncthreads();
  float* sS = Et;                    // [64 m][16 tk]
  int* sI = (int*)(Et + 1024);       // [64 m][16 tk]
  float* sS2 = Et + 2048;            // [64 m][16 tk]
  int* sIdx = (int*)(Et + 3072);     // [64 m]
  int* sFlag = (int*)(Et + 3136);    // [64 m]
  double* rd = (double*)(Et + 4096); // [256]
  int* rk = (int*)(Et + 4608);       // [256]
#pragma unroll
  for (int i = 0; i < 4; ++i) {
    int m = tm * 4 + i;
    sS[m * 16 + tk] = bestS[i];
    sI[m * 16 + tk] = bestI[i];
    sS2[m * 16 + tk] = best2[i];
  }
  __syncthreads();
  if (tid < 64) {
    int m = tid;
    float g1 = -3.4e38f, g2 = -3.4e38f;
    int gi = 0;
    for (int t = 0; t < 16; ++t) {
      float s = sS[m * 16 + t];
      int id = sI[m * 16 + t];
      if (s > g1) { g2 = g1; g1 = s; gi = id; }
      else {
        if (s == g1 && id < gi) gi = id;  // exact tie -> also flagged via g2==g1
        if (s > g2) g2 = s;
      }
      float s2 = sS2[m * 16 + t];
      if (s2 > g2) g2 = s2;
    }
    sIdx[m] = gi;
    sFlag[m] = (g1 - g2 < MARGIN) ? 1 : 0;
  }
  __syncthreads();

  // fp64 refinement for near-tie rows (rare: ~1% of rows -> ~0.3 per block)
  for (int m = 0; m < 64; ++m) {
    if (!sFlag[m]) continue;
    double bd = 1e300;
    int bk = 0;
    for (int t = 0; t < 4; ++t) {
      int k = t * 256 + tid;  // ascending within thread
      const float* er = cbn + (size_t)k * D_;
      double d = 0.0;
      for (int dd = 0; dd < 128; ++dd) {
        double df = (double)Xt[dd * 64 + m] - (double)er[dd];
        d = fma(df, df, d);
      }
      if (d < bd || (d == bd && k < bk)) { bd = d; bk = k; }
    }
    rd[tid] = bd;
    rk[tid] = bk;
    __syncthreads();
    if (tid == 0) {
      double gb = rd[0];
      int gk = rk[0];
      for (int t = 1; t < 256; ++t) {
        if (rd[t] < gb || (rd[t] == gb && rk[t] < gk)) { gb = rd[t]; gk = rk[t]; }
      }
      sIdx[m] = gk;
    }
    __syncthreads();
  }
  __syncthreads();

  // emit indices + histogram
  if (tid < 64) {
    int bi = sIdx[tid];
    out[IDX_OFF + (b * 4 + n) * 1024 + hw0 + tid] = (float)bi;
    atomicAdd(ws + WS_CNT + n * K_ + bi, 1.0f);
  }
  __syncthreads();

  // quantized write (coalesced in m) + loss partial
  float* out0 = out + (size_t)((b * 4 + n) * 128) * 1024 + hw0;
  float lp = 0.f;
#pragma unroll 4
  for (int it = 0; it < 32; ++it) {
    int e2 = it * 256 + tid;
    int m = e2 & 63;
    int d = e2 >> 6;
    float q = cbn[sIdx[m] * 128 + d];
    float xv = Xt[d * 64 + m];
    out0[d * 1024 + m] = q;
    float df = q - xv;
    lp = fmaf(df, df, lp);
  }
#pragma unroll
  for (int off = 32; off; off >>= 1) lp += __shfl_down(lp, off, 64);
  if ((tid & 63) == 0) atomicAdd(ws + WS_LOSS + n, lp);
}

// --- finalize: loss scale + perplexity ---
__global__ void vq_finalize(const float* __restrict__ ws, float* __restrict__ out) {
  int n = blockIdx.x;
  int t = threadIdx.x;
  const float* counts = ws + WS_CNT + n * K_;
  float s = 0.f;
  for (int k = t; k < K_; k += 256) {
    float p = counts[k] * (1.0f / 32768.0f);
    s += p * logf(p + 1e-10f);
  }
  __shared__ float red[4];
#pragma unroll
  for (int off = 32; off; off >>= 1) s += __shfl_down(s, off, 64);
  if ((t & 63) == 0) red[t >> 6] = s;
  __syncthreads();
  if (t == 0) {
    s = red[0] + red[1] + red[2] + red[3];
    out[PERP_OFF + n] = expf(-s);
    out[LOSS_OFF + n] = 1.25f * ws[WS_LOSS + n] / 4194304.0f;
  }
}

extern "C" void kernel_launch(void* const* d_in, const int* in_sizes, int n_in,
                              void* d_out, int out_size, void* d_ws, size_t ws_size,
                              hipStream_t stream) {
  const float* x = (const float*)d_in[0];
  const float* cb = (const float*)d_in[1];
  float* out = (float*)d_out;
  float* ws = (float*)d_ws;
  // zero loss + histogram accumulators (ws is poisoned 0xAA before each call)
  hipMemsetAsync(d_ws, 0, (WS_CNT + 4096) * sizeof(float), stream);
  vq_prep<<<16, 256, 0, stream>>>(cb, ws);
  vq_main<<<2048, 256, 0, stream>>>(x, cb, ws, out);
  vq_finalize<<<4, 256, 0, stream>>>(ws, out);
}

// Round 3
// 496.144 us; speedup vs baseline: 1.7008x; 1.7008x over previous
//
#include <hip/hip_runtime.h>

#define B_ 32
#define N_ 4
#define D_ 128
#define M_ 32768
#define K_ 1024

#define IDX_OFF 16777216
#define LOSS_OFF 16908288
#define PERP_OFF 16908292

// ws float-index layout
#define WS_LOSS 0          // 4 floats
#define WS_CNT 1024        // 4*1024 floats
#define WS_ENORM 8192      // 4*1024 floats (0.5*||e||^2, fp32)
#define WS_BPACK_F 16384   // packed split-bf16 codebook: 4 layers * 256KB hi+lo = 2MB
#define BPACK_LAYER_US 262144  // ushorts per layer: 64 tiles * 4 ks * 2(hi/lo) * 64 lanes * 8

#define MARGIN 0.03f

typedef __bf16 bf16x8 __attribute__((ext_vector_type(8)));
typedef float f32x4 __attribute__((ext_vector_type(4)));

union FragU {
  bf16x8 v;
  uint u32[4];
  ushort u16[8];
  uint4 q;
};

__device__ __forceinline__ ushort bf16_hi_rne(float f, float* hif) {
  uint u = __float_as_uint(f);
  uint r = (u + 0x7fffu + ((u >> 16) & 1u)) >> 16;
  *hif = __uint_as_float(r << 16);
  return (ushort)r;
}
__device__ __forceinline__ ushort bf16_rne(float f) {
  uint u = __float_as_uint(f);
  return (ushort)((u + 0x7fffu + ((u >> 16) & 1u)) >> 16);
}

// --- prep: pack codebook into MFMA-fragment-ordered split-bf16 + enorm ---
__global__ void vq_pack(const float* __restrict__ cb, float* __restrict__ ws) {
  int blk = blockIdx.x, tid = threadIdx.x;
  if (blk < 256) {
    int n = blk >> 6, tile = blk & 63;
    int s = tid >> 6, lane = tid & 63;
    int code = tile * 16 + (lane & 15);
    int dbase = s * 32 + ((lane >> 4) << 3);
    const float* src = cb + ((size_t)(n * K_ + code)) * D_ + dbase;
    float4 v0 = *(const float4*)src;
    float4 v1 = *(const float4*)(src + 4);
    float v[8] = {v0.x, v0.y, v0.z, v0.w, v1.x, v1.y, v1.z, v1.w};
    FragU fh, fl;
#pragma unroll
    for (int j = 0; j < 8; ++j) {
      float hif;
      fh.u16[j] = bf16_hi_rne(v[j], &hif);
      fl.u16[j] = bf16_rne(v[j] - hif);
    }
    ushort* base = (ushort*)(ws + WS_BPACK_F) + (size_t)n * BPACK_LAYER_US +
                   ((size_t)(tile * 4 + s) * 2) * 512 + lane * 8;
    *(uint4*)base = fh.q;          // hi half of (tile,s)
    *(uint4*)(base + 512) = fl.q;  // lo half
  } else {
    int t = (blk - 256) * 256 + tid;  // 0..4095
    int n = t >> 10, k = t & 1023;
    const float* row = cb + (size_t)(n * K_ + k) * D_;
    float ss = 0.f;
#pragma unroll 4
    for (int d = 0; d < D_; ++d) ss = fmaf(row[d], row[d], ss);
    ws[WS_ENORM + t] = 0.5f * ss;
  }
}

// --- main: split-bf16 MFMA score GEMM + fused top-2 + fp64 refine + outputs ---
__global__ __launch_bounds__(256, 3) void vq_main(const float* __restrict__ x,
                                                  const float* __restrict__ cb,
                                                  float* __restrict__ ws,
                                                  float* __restrict__ out) {
  __shared__ alignas(16) ushort Bsm[16384];  // 32KB staging, later reduce scratch
  const int tid = threadIdx.x;
  const int bid = blockIdx.x;
  const int n = bid >> 8;
  const int mblk = bid & 255;      // 256 m-tiles of 128 rows per layer
  const int b = mblk >> 3;
  const int hw0 = (mblk & 7) << 7;

  const int lane = tid & 63, w = tid >> 6;
  const int quad = lane >> 4, l15 = lane & 15;

  const float* xbase = x + (size_t)((b * 4 + n) * 128) * 1024 + hw0;
  const float* cbn = cb + (size_t)n * K_ * D_;
  const float* enorm_n = ws + WS_ENORM + n * K_;
  const ushort* bpack_n = (ushort*)(ws + WS_BPACK_F) + (size_t)n * BPACK_LAYER_US;

  // ---- build A fragments in registers (32 m-rows per wave, 2 sets of 16) ----
  bf16x8 ahi[2][4], alo[2][4];
#pragma unroll
  for (int set = 0; set < 2; ++set) {
    const int hwl = w * 32 + set * 16 + l15;
#pragma unroll
    for (int s = 0; s < 4; ++s) {
      const int dbase = s * 32 + quad * 8;
      FragU fh, fl;
#pragma unroll
      for (int j = 0; j < 8; ++j) {
        float v = xbase[(size_t)(dbase + j) * 1024 + hwl];
        float hif;
        fh.u16[j] = bf16_hi_rne(v, &hif);
        fl.u16[j] = bf16_rne(v - hif);
      }
      ahi[set][s] = fh.v;
      alo[set][s] = fl.v;
    }
  }

  float best[8], best2[8];
  int bestT[8];
#pragma unroll
  for (int i = 0; i < 8; ++i) { best[i] = -3.4e38f; best2[i] = -3.4e38f; bestT[i] = 0; }

  const uint4* gsrc = (const uint4*)bpack_n;  // layer = 32768 uint4
  uint4* Bsm4 = (uint4*)Bsm;

  // ---- K loop: 16 chunks x 4 tiles (16 codes each) ----
  for (int c = 0; c < 16; ++c) {
    __syncthreads();
#pragma unroll
    for (int i = 0; i < 8; ++i) Bsm4[tid + i * 256] = gsrc[c * 2048 + tid + i * 256];
    __syncthreads();
#pragma unroll 2
    for (int tin = 0; tin < 4; ++tin) {
      const int t = c * 4 + tin;
      float en = enorm_n[t * 16 + l15];
      bf16x8 bh[4], bl[4];
#pragma unroll
      for (int s = 0; s < 4; ++s) {
        const ushort* p = Bsm + ((tin * 4 + s) * 2) * 512 + lane * 8;
        bh[s] = ((const FragU*)p)->v;
        bl[s] = ((const FragU*)(p + 512))->v;
      }
      f32x4 acc0 = {0.f, 0.f, 0.f, 0.f};
      f32x4 acc1 = {0.f, 0.f, 0.f, 0.f};
#pragma unroll
      for (int s = 0; s < 4; ++s) {
        acc0 = __builtin_amdgcn_mfma_f32_16x16x32_bf16(ahi[0][s], bh[s], acc0, 0, 0, 0);
        acc1 = __builtin_amdgcn_mfma_f32_16x16x32_bf16(ahi[1][s], bh[s], acc1, 0, 0, 0);
        acc0 = __builtin_amdgcn_mfma_f32_16x16x32_bf16(ahi[0][s], bl[s], acc0, 0, 0, 0);
        acc1 = __builtin_amdgcn_mfma_f32_16x16x32_bf16(ahi[1][s], bl[s], acc1, 0, 0, 0);
        acc0 = __builtin_amdgcn_mfma_f32_16x16x32_bf16(alo[0][s], bh[s], acc0, 0, 0, 0);
        acc1 = __builtin_amdgcn_mfma_f32_16x16x32_bf16(alo[1][s], bh[s], acc1, 0, 0, 0);
      }
      // fused top-2 epilogue (k ascending per lane via t ascending; strict >)
#pragma unroll
      for (int r = 0; r < 4; ++r) {
        float s0 = acc0[r] - en;
        float nb2 = fmaxf(fminf(s0, best[r]), best2[r]);  // med3
        bool cg = s0 > best[r];
        best[r] = fmaxf(s0, best[r]);
        bestT[r] = cg ? t : bestT[r];
        best2[r] = nb2;
        float s1 = acc1[r] - en;
        float nb2b = fmaxf(fminf(s1, best[4 + r]), best2[4 + r]);
        bool cg1 = s1 > best[4 + r];
        best[4 + r] = fmaxf(s1, best[4 + r]);
        bestT[4 + r] = cg1 ? t : bestT[4 + r];
        best2[4 + r] = nb2b;
      }
    }
  }

  // ---- cross-lane reduce over the 16 code-sublanes ----
  __syncthreads();
  float* sS = (float*)Bsm;                 // [128][16]  (8KB)
  int* sI = (int*)(Bsm + 4096);            // [128][16]  (8KB)
  float* sS2 = (float*)(Bsm + 8192);       // [128][16]  (8KB)
  int* sIdx = (int*)(Bsm + 12288);         // [128]
  int* sFlag = (int*)(Bsm + 12544);        // [128]
  float* xrow = (float*)(Bsm + 12800);     // [128]
  double* rd = (double*)(Bsm + 13056);     // [256] (8B-aligned: 26112 bytes)
  int* rk = (int*)(Bsm + 15104);           // [256]

#pragma unroll
  for (int set = 0; set < 2; ++set) {
#pragma unroll
    for (int r = 0; r < 4; ++r) {
      int m = w * 32 + set * 16 + quad * 4 + r;
      sS[m * 16 + l15] = best[set * 4 + r];
      sS2[m * 16 + l15] = best2[set * 4 + r];
      sI[m * 16 + l15] = bestT[set * 4 + r] * 16 + l15;
    }
  }
  __syncthreads();
  if (tid < 128) {
    int m = tid;
    float g1 = -3.4e38f, g2 = -3.4e38f;
    int gi = 0;
    for (int t = 0; t < 16; ++t) {
      float s = sS[m * 16 + t];
      int id = sI[m * 16 + t];
      if (s > g1) { g2 = g1; g1 = s; gi = id; }
      else {
        if (s == g1 && id < gi) gi = id;
        if (s > g2) g2 = s;
      }
      float s2 = sS2[m * 16 + t];
      if (s2 > g2) g2 = s2;
    }
    sIdx[m] = gi;
    sFlag[m] = (g1 - g2 < MARGIN) ? 1 : 0;
  }
  __syncthreads();

  // ---- fp64 refinement for near-tie rows (rare) ----
  for (int m = 0; m < 128; ++m) {
    if (!sFlag[m]) continue;
    if (tid < 128) xrow[tid] = xbase[(size_t)tid * 1024 + m];
    __syncthreads();
    double bd = 1e300;
    int bk = 0;
    for (int tl = 0; tl < 4; ++tl) {
      int k = tl * 256 + tid;
      const float* er = cbn + (size_t)k * D_;
      double d = 0.0;
      for (int dd = 0; dd < 128; ++dd) {
        double df = (double)xrow[dd] - (double)er[dd];
        d = fma(df, df, d);
      }
      if (d < bd || (d == bd && k < bk)) { bd = d; bk = k; }
    }
    rd[tid] = bd;
    rk[tid] = bk;
    __syncthreads();
    if (tid == 0) {
      double gb = rd[0];
      int gk = rk[0];
      for (int t = 1; t < 256; ++t)
        if (rd[t] < gb || (rd[t] == gb && rk[t] < gk)) { gb = rd[t]; gk = rk[t]; }
      sIdx[m] = gk;
    }
    __syncthreads();
  }
  __syncthreads();

  // ---- indices + histogram ----
  if (tid < 128) {
    int bi = sIdx[tid];
    out[IDX_OFF + (b * 4 + n) * 1024 + hw0 + tid] = (float)bi;
    atomicAdd(ws + WS_CNT + n * K_ + bi, 1.0f);
  }
  __syncthreads();

  // ---- quantized gather (float4 over m) + loss partial ----
  float* out0 = out + (size_t)((b * 4 + n) * 128) * 1024 + hw0;
  float lp = 0.f;
#pragma unroll 4
  for (int it = 0; it < 16; ++it) {
    int e = it * 256 + tid;      // 4096 float4s
    int m4 = (e & 31) * 4;
    int d = e >> 5;
    float4 xv = *(const float4*)(xbase + (size_t)d * 1024 + m4);
    float4 q;
    q.x = cbn[(size_t)sIdx[m4 + 0] * D_ + d];
    q.y = cbn[(size_t)sIdx[m4 + 1] * D_ + d];
    q.z = cbn[(size_t)sIdx[m4 + 2] * D_ + d];
    q.w = cbn[(size_t)sIdx[m4 + 3] * D_ + d];
    *(float4*)(out0 + (size_t)d * 1024 + m4) = q;
    float dx = q.x - xv.x, dy = q.y - xv.y, dz = q.z - xv.z, dw = q.w - xv.w;
    lp = fmaf(dx, dx, lp);
    lp = fmaf(dy, dy, lp);
    lp = fmaf(dz, dz, lp);
    lp = fmaf(dw, dw, lp);
  }
#pragma unroll
  for (int off = 32; off; off >>= 1) lp += __shfl_down(lp, off, 64);
  if (lane == 0) atomicAdd(ws + WS_LOSS + n, lp);
}

// --- finalize: loss scale + perplexity ---
__global__ void vq_finalize(const float* __restrict__ ws, float* __restrict__ out) {
  int n = blockIdx.x;
  int t = threadIdx.x;
  const float* counts = ws + WS_CNT + n * K_;
  float s = 0.f;
  for (int k = t; k < K_; k += 256) {
    float p = counts[k] * (1.0f / 32768.0f);
    s += p * logf(p + 1e-10f);
  }
  __shared__ float red[4];
#pragma unroll
  for (int off = 32; off; off >>= 1) s += __shfl_down(s, off, 64);
  if ((t & 63) == 0) red[t >> 6] = s;
  __syncthreads();
  if (t == 0) {
    s = red[0] + red[1] + red[2] + red[3];
    out[PERP_OFF + n] = expf(-s);
    out[LOSS_OFF + n] = 1.25f * ws[WS_LOSS + n] / 4194304.0f;
  }
}

extern "C" void kernel_launch(void* const* d_in, const int* in_sizes, int n_in,
                              void* d_out, int out_size, void* d_ws, size_t ws_size,
                              hipStream_t stream) {
  const float* x = (const float*)d_in[0];
  const float* cb = (const float*)d_in[1];
  float* out = (float*)d_out;
  float* ws = (float*)d_ws;
  hipMemsetAsync(d_ws, 0, 5120 * sizeof(float), stream);  // loss + counts
  vq_pack<<<272, 256, 0, stream>>>(cb, ws);
  vq_main<<<1024, 256, 0, stream>>>(x, cb, ws, out);
  vq_finalize<<<4, 256, 0, stream>>>(ws, out);
}

// Round 4
// 322.797 us; speedup vs baseline: 2.6142x; 1.5370x over previous
//
#include <hip/hip_runtime.h>

#define B_ 32
#define N_ 4
#define D_ 128
#define M_ 32768
#define K_ 1024

#define IDX_OFF 16777216
#define LOSS_OFF 16908288
#define PERP_OFF 16908292

// ws float-index layout
#define WS_LOSS 0          // 4 floats
#define WS_CNT 1024        // 4*1024 floats
#define WS_ENORM 8192      // 4*1024 floats (biased: 384 - 0.5*||e||^2)
#define WS_BPACK_F 16384   // packed split-bf16 codebook: 4 layers * 512KB = 2MB
#define BPACK_LAYER_US 262144  // ushorts per layer

#define SBIAS 384.0f
#define MARGIN 0.012f

typedef __bf16 bf16x8 __attribute__((ext_vector_type(8)));
typedef float f32x4 __attribute__((ext_vector_type(4)));

union FragU {
  bf16x8 v;
  ushort u16[8];
  uint4 q;
};

__device__ __forceinline__ ushort bf16_hi_rne(float f, float* hif) {
  uint u = __float_as_uint(f);
  uint r = (u + 0x7fffu + ((u >> 16) & 1u)) >> 16;
  *hif = __uint_as_float(r << 16);
  return (ushort)r;
}
__device__ __forceinline__ ushort bf16_rne(float f) {
  uint u = __float_as_uint(f);
  return (ushort)((u + 0x7fffu + ((u >> 16) & 1u)) >> 16);
}

__device__ __forceinline__ void gload_lds16(const void* g, void* l) {
  __builtin_amdgcn_global_load_lds(
      (const __attribute__((address_space(1))) unsigned int*)g,
      (__attribute__((address_space(3))) unsigned int*)l, 16, 0, 0);
}

// --- prep: pack codebook into MFMA-fragment-ordered split-bf16 + biased enorm ---
__global__ void vq_pack(const float* __restrict__ cb, float* __restrict__ ws) {
  int blk = blockIdx.x, tid = threadIdx.x;
  if (blk < 256) {
    int n = blk >> 6, tile = blk & 63;
    int s = tid >> 6, lane = tid & 63;
    int code = tile * 16 + (lane & 15);
    int dbase = s * 32 + ((lane >> 4) << 3);
    const float* src = cb + ((size_t)(n * K_ + code)) * D_ + dbase;
    float4 v0 = *(const float4*)src;
    float4 v1 = *(const float4*)(src + 4);
    float v[8] = {v0.x, v0.y, v0.z, v0.w, v1.x, v1.y, v1.z, v1.w};
    FragU fh, fl;
#pragma unroll
    for (int j = 0; j < 8; ++j) {
      float hif;
      fh.u16[j] = bf16_hi_rne(v[j], &hif);
      fl.u16[j] = bf16_rne(v[j] - hif);
    }
    ushort* base = (ushort*)(ws + WS_BPACK_F) + (size_t)n * BPACK_LAYER_US +
                   ((size_t)(tile * 4 + s) * 2) * 512 + lane * 8;
    *(uint4*)base = fh.q;
    *(uint4*)(base + 512) = fl.q;
  } else {
    int t = (blk - 256) * 256 + tid;
    int n = t >> 10, k = t & 1023;
    const float* row = cb + (size_t)(n * K_ + k) * D_;
    float ss = 0.f;
#pragma unroll 4
    for (int d = 0; d < D_; ++d) ss = fmaf(row[d], row[d], ss);
    ws[WS_ENORM + t] = SBIAS - 0.5f * ss;
  }
}

// --- main ---
__global__ __launch_bounds__(256, 2) void vq_main(const float* __restrict__ x,
                                                  const float* __restrict__ cb,
                                                  float* __restrict__ ws,
                                                  float* __restrict__ out) {
  __shared__ alignas(16) ushort Bsm[32768];  // 64KB: 2x32KB double buffer; reused after
  const int tid = threadIdx.x;
  const int bid = blockIdx.x;
  const int n = bid >> 7;          // 4 layers x 128 m-tiles of 256 rows
  const int mblk = bid & 127;
  const int b = mblk >> 2;
  const int hw0 = (mblk & 3) << 8;

  const int lane = tid & 63, w = tid >> 6;
  const int quad = lane >> 4, l15 = lane & 15;

  const float* xbase = x + (size_t)((b * 4 + n) * 128) * 1024 + hw0;
  const float* cbn = cb + (size_t)n * K_ * D_;
  const float* enB = ws + WS_ENORM + n * K_;
  const ushort* bpack_n = (ushort*)(ws + WS_BPACK_F) + (size_t)n * BPACK_LAYER_US;

  // ---- A fragments in registers: 64 rows/wave, 4 sets of 16 ----
  bf16x8 ahi[4][4], alo[4][4];
#pragma unroll
  for (int set = 0; set < 4; ++set) {
    const int hwl = w * 64 + set * 16 + l15;
#pragma unroll
    for (int s = 0; s < 4; ++s) {
      const int dbase = s * 32 + quad * 8;
      FragU fh, fl;
#pragma unroll
      for (int j = 0; j < 8; ++j) {
        float v = xbase[(size_t)(dbase + j) * 1024 + hwl];
        float hif;
        fh.u16[j] = bf16_hi_rne(v, &hif);
        fl.u16[j] = bf16_rne(v - hif);
      }
      ahi[set][s] = fh.v;
      alo[set][s] = fl.v;
    }
  }

  uint best[16], best2[16];
#pragma unroll
  for (int i = 0; i < 16; ++i) { best[i] = 0u; best2[i] = 0u; }

  const uint4* gsrc = (const uint4*)bpack_n;  // 32768 uint4/layer
  uint4* Bsm4 = (uint4*)Bsm;

  // prologue stage chunk 0 into buf0
#pragma unroll
  for (int i = 0; i < 8; ++i)
    gload_lds16(gsrc + i * 256 + w * 64 + lane, Bsm4 + i * 256 + w * 64);

#pragma unroll 1
  for (int c = 0; c < 16; ++c) {
    __syncthreads();  // publishes stage(c); drains its vmcnt
    if (c < 15) {
      const uint4* src = gsrc + (c + 1) * 2048;
      uint4* dst = Bsm4 + ((c + 1) & 1) * 2048;
#pragma unroll
      for (int i = 0; i < 8; ++i)
        gload_lds16(src + i * 256 + w * 64 + lane, dst + i * 256 + w * 64);
    }
    const ushort* Bcur = Bsm + (c & 1) * 16384;
#pragma unroll 1
    for (int tin = 0; tin < 4; ++tin) {
      const int t = c * 4 + tin;
      const uint tinv = (uint)(63 - t);
      float en = enB[t * 16 + l15];
      bf16x8 bh[4], bl[4];
#pragma unroll
      for (int s = 0; s < 4; ++s) {
        const ushort* p = Bcur + ((tin * 4 + s) * 2) * 512 + lane * 8;
        bh[s] = ((const FragU*)p)->v;
        bl[s] = ((const FragU*)(p + 512))->v;
      }
      f32x4 acc[4];
#pragma unroll
      for (int set = 0; set < 4; ++set) acc[set] = (f32x4){0.f, 0.f, 0.f, 0.f};
#pragma unroll
      for (int s = 0; s < 4; ++s) {
#pragma unroll
        for (int set = 0; set < 4; ++set)
          acc[set] = __builtin_amdgcn_mfma_f32_16x16x32_bf16(ahi[set][s], bh[s], acc[set], 0, 0, 0);
#pragma unroll
        for (int set = 0; set < 4; ++set)
          acc[set] = __builtin_amdgcn_mfma_f32_16x16x32_bf16(ahi[set][s], bl[s], acc[set], 0, 0, 0);
#pragma unroll
        for (int set = 0; set < 4; ++set)
          acc[set] = __builtin_amdgcn_mfma_f32_16x16x32_bf16(alo[set][s], bh[s], acc[set], 0, 0, 0);
      }
      // packed top-2 epilogue: key = (bits(score+bias) & ~63) | (63-t)
#pragma unroll
      for (int set = 0; set < 4; ++set) {
#pragma unroll
        for (int r = 0; r < 4; ++r) {
          float sb = acc[set][r] + en;
          uint key = (__float_as_uint(sb) & 0xFFFFFFC0u) | tinv;
          uint ob = best[set * 4 + r];
          uint mn = key < ob ? key : ob;
          best[set * 4 + r] = key > ob ? key : ob;
          if (mn > best2[set * 4 + r]) best2[set * 4 + r] = mn;
        }
      }
    }
  }
  __syncthreads();  // done with B buffers; overlay LDS

  // LDS overlays (byte offsets into Bsm)
  uint* sS = (uint*)Bsm;                       // [256][17] = 17408 B
  uint* sS2 = (uint*)((char*)Bsm + 17408);     // [256][17]
  int* sIdx = (int*)((char*)Bsm + 34816);      // [256]
  int* list = (int*)((char*)Bsm + 35840);      // [256]
  int* lcnt = (int*)((char*)Bsm + 36864);      // [1]
  double* xrowd = (double*)((char*)Bsm + 36872);  // [128]
  double* rd = (double*)((char*)Bsm + 37896);  // [4]
  int* rk = (int*)((char*)Bsm + 37928);        // [4]

  if (tid == 0) *lcnt = 0;
#pragma unroll
  for (int set = 0; set < 4; ++set) {
#pragma unroll
    for (int r = 0; r < 4; ++r) {
      int m = w * 64 + set * 16 + quad * 4 + r;
      sS[m * 17 + l15] = best[set * 4 + r];
      sS2[m * 17 + l15] = best2[set * 4 + r];
    }
  }
  __syncthreads();

  // per-row reduce over the 16 code-sublanes (one row per thread)
  {
    int m = tid;
    uint g1 = 0, g2 = 0;
    int gi = 0;
#pragma unroll 4
    for (int li = 0; li < 16; ++li) {
      uint key = sS[m * 17 + li];
      uint sb = key >> 6;
      int kk = (int)(63u - (key & 63u)) * 16 + li;
      if (sb > g1) { g2 = g1; g1 = sb; gi = kk; }
      else {
        if (sb == g1 && kk < gi) gi = kk;
        if (sb > g2) g2 = sb;
      }
      uint sb2 = sS2[m * 17 + li] >> 6;
      if (sb2 > g2) g2 = sb2;
    }
    sIdx[m] = gi;
    float gap = __uint_as_float(g1 << 6) - __uint_as_float(g2 << 6);
    if (gap < MARGIN) {
      int pos = atomicAdd(lcnt, 1);
      list[pos] = m;
    }
  }
  __syncthreads();

  // ---- block-cooperative fp64 refine for flagged rows (rare) ----
  const int cnt = *lcnt;
  for (int i = 0; i < cnt; ++i) {
    const int m = list[i];
    if (tid < 128) xrowd[tid] = (double)xbase[(size_t)tid * 1024 + m];
    __syncthreads();
    double bd = 1e300;
    int bk = 0;
#pragma unroll 1
    for (int j = 0; j < 4; ++j) {
      const int k = tid * 4 + j;
      const float4* er = (const float4*)(cbn + (size_t)k * D_);
      double d = 0.0;
#pragma unroll 8
      for (int c4 = 0; c4 < 32; ++c4) {
        float4 e = er[c4];
        double d0 = xrowd[c4 * 4 + 0] - (double)e.x;
        double d1 = xrowd[c4 * 4 + 1] - (double)e.y;
        double d2 = xrowd[c4 * 4 + 2] - (double)e.z;
        double d3 = xrowd[c4 * 4 + 3] - (double)e.w;
        d = fma(d0, d0, d);
        d = fma(d1, d1, d);
        d = fma(d2, d2, d);
        d = fma(d3, d3, d);
      }
      if (d < bd) { bd = d; bk = k; }  // j ascending => first occurrence kept
    }
#pragma unroll
    for (int off = 32; off; off >>= 1) {
      double od = __shfl_down(bd, off, 64);
      int ok = __shfl_down(bk, off, 64);
      if (od < bd || (od == bd && ok < bk)) { bd = od; bk = ok; }
    }
    if (lane == 0) { rd[w] = bd; rk[w] = bk; }
    __syncthreads();
    if (tid == 0) {
      double gb = rd[0];
      int gk = rk[0];
      for (int t = 1; t < 4; ++t)
        if (rd[t] < gb || (rd[t] == gb && rk[t] < gk)) { gb = rd[t]; gk = rk[t]; }
      sIdx[m] = gk;
    }
    __syncthreads();
  }

  // ---- indices + histogram (one row per thread) ----
  {
    int bi = sIdx[tid];
    out[IDX_OFF + (b * 4 + n) * 1024 + hw0 + tid] = (float)bi;
    atomicAdd(ws + WS_CNT + n * K_ + bi, 1.0f);
  }
  __syncthreads();

  // ---- quantized gather (float4 over m) + loss partial ----
  float* out0 = out + (size_t)((b * 4 + n) * 128) * 1024 + hw0;
  float lp = 0.f;
#pragma unroll 4
  for (int it = 0; it < 32; ++it) {
    int e = it * 256 + tid;      // 8192 float4s
    int m4 = (e & 63) * 4;
    int d = e >> 6;
    float4 xv = *(const float4*)(xbase + (size_t)d * 1024 + m4);
    float4 q;
    q.x = cbn[(size_t)sIdx[m4 + 0] * D_ + d];
    q.y = cbn[(size_t)sIdx[m4 + 1] * D_ + d];
    q.z = cbn[(size_t)sIdx[m4 + 2] * D_ + d];
    q.w = cbn[(size_t)sIdx[m4 + 3] * D_ + d];
    *(float4*)(out0 + (size_t)d * 1024 + m4) = q;
    float dx = q.x - xv.x, dy = q.y - xv.y, dz = q.z - xv.z, dw = q.w - xv.w;
    lp = fmaf(dx, dx, lp);
    lp = fmaf(dy, dy, lp);
    lp = fmaf(dz, dz, lp);
    lp = fmaf(dw, dw, lp);
  }
#pragma unroll
  for (int off = 32; off; off >>= 1) lp += __shfl_down(lp, off, 64);
  if (lane == 0) atomicAdd(ws + WS_LOSS + n, lp);
}

// --- finalize: loss scale + perplexity ---
__global__ void vq_finalize(const float* __restrict__ ws, float* __restrict__ out) {
  int n = blockIdx.x;
  int t = threadIdx.x;
  const float* counts = ws + WS_CNT + n * K_;
  float s = 0.f;
  for (int k = t; k < K_; k += 256) {
    float p = counts[k] * (1.0f / 32768.0f);
    s += p * logf(p + 1e-10f);
  }
  __shared__ float red[4];
#pragma unroll
  for (int off = 32; off; off >>= 1) s += __shfl_down(s, off, 64);
  if ((t & 63) == 0) red[t >> 6] = s;
  __syncthreads();
  if (t == 0) {
    s = red[0] + red[1] + red[2] + red[3];
    out[PERP_OFF + n] = expf(-s);
    out[LOSS_OFF + n] = 1.25f * ws[WS_LOSS + n] / 4194304.0f;
  }
}

extern "C" void kernel_launch(void* const* d_in, const int* in_sizes, int n_in,
                              void* d_out, int out_size, void* d_ws, size_t ws_size,
                              hipStream_t stream) {
  const float* x = (const float*)d_in[0];
  const float* cb = (const float*)d_in[1];
  float* out = (float*)d_out;
  float* ws = (float*)d_ws;
  hipMemsetAsync(d_ws, 0, 5120 * sizeof(float), stream);  // loss + counts
  vq_pack<<<272, 256, 0, stream>>>(cb, ws);
  vq_main<<<512, 256, 0, stream>>>(x, cb, ws, out);
  vq_finalize<<<4, 256, 0, stream>>>(ws, out);
}

// Round 5
// 276.455 us; speedup vs baseline: 3.0524x; 1.1676x over previous
//
#include <hip/hip_runtime.h>

#define B_ 32
#define N_ 4
#define D_ 128
#define M_ 32768
#define K_ 1024

#define IDX_OFF 16777216
#define LOSS_OFF 16908288
#define PERP_OFF 16908292

// ws float-index layout
#define WS_LOSS 0          // 4 floats
#define WS_CNT 1024        // 4*1024 floats
#define WS_ENORM 8192      // 4*1024 floats (biased: 384 - 0.5*||e||^2)
#define WS_BPACK_F 16384   // packed split-bf16 codebook: 4 layers * 512KB = 2MB
#define BPACK_LAYER_US 262144

#define SBIAS 384.0f
#define MARGIN 0.012f

typedef __bf16 bf16x8 __attribute__((ext_vector_type(8)));
typedef float f32x4 __attribute__((ext_vector_type(4)));

union FragU {
  bf16x8 v;
  ushort u16[8];
  uint4 q;
};

__device__ __forceinline__ ushort bf16_hi_rne(float f, float* hif) {
  uint u = __float_as_uint(f);
  uint r = (u + 0x7fffu + ((u >> 16) & 1u)) >> 16;
  *hif = __uint_as_float(r << 16);
  return (ushort)r;
}
__device__ __forceinline__ ushort bf16_rne(float f) {
  uint u = __float_as_uint(f);
  return (ushort)((u + 0x7fffu + ((u >> 16) & 1u)) >> 16);
}

__device__ __forceinline__ void gload_lds16(const void* g, void* l) {
  __builtin_amdgcn_global_load_lds(
      (const __attribute__((address_space(1))) unsigned int*)g,
      (__attribute__((address_space(3))) unsigned int*)l, 16, 0, 0);
}

// --- prep: pack codebook (fragment order, split-bf16) + enorm + zero accum ---
__global__ void vq_pack(const float* __restrict__ cb, float* __restrict__ ws) {
  int blk = blockIdx.x, tid = threadIdx.x;
  if (blk < 256) {
    int n = blk >> 6, tile = blk & 63;
    int s = tid >> 6, lane = tid & 63;
    int code = tile * 16 + (lane & 15);
    int dbase = s * 32 + ((lane >> 4) << 3);
    const float* src = cb + ((size_t)(n * K_ + code)) * D_ + dbase;
    float4 v0 = *(const float4*)src;
    float4 v1 = *(const float4*)(src + 4);
    float v[8] = {v0.x, v0.y, v0.z, v0.w, v1.x, v1.y, v1.z, v1.w};
    FragU fh, fl;
#pragma unroll
    for (int j = 0; j < 8; ++j) {
      float hif;
      fh.u16[j] = bf16_hi_rne(v[j], &hif);
      fl.u16[j] = bf16_rne(v[j] - hif);
    }
    ushort* base = (ushort*)(ws + WS_BPACK_F) + (size_t)n * BPACK_LAYER_US +
                   ((size_t)(tile * 4 + s) * 2) * 512 + lane * 8;
    *(uint4*)base = fh.q;
    *(uint4*)(base + 512) = fl.q;
  } else if (blk < 1280) {
    // enorm: one wave per code, coalesced float2 + shuffle reduce
    int lane = tid & 63, w = tid >> 6;
    int waveid = (blk - 256) * 4 + w;  // 0..4095
    int n = waveid >> 10, k = waveid & 1023;
    const float2* row = (const float2*)(cb + (size_t)(n * K_ + k) * D_);
    float2 v = row[lane];
    float ss = fmaf(v.x, v.x, v.y * v.y);
#pragma unroll
    for (int off = 32; off; off >>= 1) ss += __shfl_down(ss, off, 64);
    if (lane == 0) ws[WS_ENORM + n * K_ + k] = SBIAS - 0.5f * ss;
  } else {
    // zero loss + histogram
#pragma unroll
    for (int i = 0; i < 20; ++i) ws[i * 256 + tid] = 0.f;
  }
}

// --- main ---
__global__ __launch_bounds__(256, 4) void vq_main(const float* __restrict__ x,
                                                  const float* __restrict__ cb,
                                                  float* __restrict__ ws,
                                                  float* __restrict__ out) {
  __shared__ alignas(16) ushort Bsm[18432];  // 36 KB: 2x16KB dbuf + 4KB persistent
  const int tid = threadIdx.x;
  const int bid = blockIdx.x;
  const int n = bid >> 8;          // 4 layers x 256 m-tiles of 128 rows
  const int mblk = bid & 255;
  const int b = mblk >> 3;
  const int hw0 = (mblk & 7) << 7;

  const int lane = tid & 63, w = tid >> 6;
  const int quad = lane >> 4, l15 = lane & 15;

  const float* xbase = x + (size_t)((b * 4 + n) * 128) * 1024 + hw0;
  const float* cbn = cb + (size_t)n * K_ * D_;
  const float* enB = ws + WS_ENORM + n * K_;
  const ushort* bpack_n = (ushort*)(ws + WS_BPACK_F) + (size_t)n * BPACK_LAYER_US;

  // persistent LDS region (beyond the 32KB staging buffers)
  char* ext = (char*)Bsm + 32768;
  int* sIdx = (int*)ext;                  // [128]
  float* dist = (float*)(ext + 512);      // [128]  (holds ||x||^2, then dist^2)
  int* list = (int*)(ext + 1024);         // [128]
  int* lcnt = (int*)(ext + 1536);         // [1]
  double* xrowd = (double*)(ext + 1544);  // [128]
  double* rd = (double*)(ext + 2568);     // [4]
  int* rk = (int*)(ext + 2600);           // [4]

  if (tid == 0) *lcnt = 0;

  // ---- A fragments in registers: 32 rows/wave, 2 sets of 16; + ||x||^2 ----
  bf16x8 ahi[2][4], alo[2][4];
#pragma unroll
  for (int set = 0; set < 2; ++set) {
    const int hwl = w * 32 + set * 16 + l15;
    float xs = 0.f;
#pragma unroll
    for (int s = 0; s < 4; ++s) {
      const int dbase = s * 32 + quad * 8;
      FragU fh, fl;
#pragma unroll
      for (int j = 0; j < 8; ++j) {
        float v = xbase[(size_t)(dbase + j) * 1024 + hwl];
        xs = fmaf(v, v, xs);
        float hif;
        fh.u16[j] = bf16_hi_rne(v, &hif);
        fl.u16[j] = bf16_rne(v - hif);
      }
      ahi[set][s] = fh.v;
      alo[set][s] = fl.v;
    }
    xs += __shfl_xor(xs, 16, 64);
    xs += __shfl_xor(xs, 32, 64);
    if (l15 == lane) dist[w * 32 + set * 16 + l15] = xs;  // lanes 0..15
  }

  uint best[8], best2[8];
#pragma unroll
  for (int i = 0; i < 8; ++i) { best[i] = 0u; best2[i] = 0u; }

  const uint4* gsrc = (const uint4*)bpack_n;  // 32768 uint4/layer
  uint4* Bsm4 = (uint4*)Bsm;

  // prologue: stage chunk 0 (16KB) into buf0
#pragma unroll
  for (int i = 0; i < 4; ++i)
    gload_lds16(gsrc + i * 256 + w * 64 + lane, Bsm4 + i * 256 + w * 64);

#pragma unroll 1
  for (int c = 0; c < 32; ++c) {
    __syncthreads();  // publishes stage(c)
    if (c < 31) {
      const uint4* src = gsrc + (c + 1) * 1024;
      uint4* dst = Bsm4 + ((c + 1) & 1) * 1024;
#pragma unroll
      for (int i = 0; i < 4; ++i)
        gload_lds16(src + i * 256 + w * 64 + lane, dst + i * 256 + w * 64);
    }
    const ushort* Bcur = Bsm + (c & 1) * 8192;
#pragma unroll
    for (int tin = 0; tin < 2; ++tin) {
      const int t = c * 2 + tin;
      const uint tinv = (uint)(63 - t);
      float en = enB[t * 16 + l15];
      bf16x8 bh[4], bl[4];
#pragma unroll
      for (int s = 0; s < 4; ++s) {
        const ushort* p = Bcur + ((tin * 4 + s) * 2) * 512 + lane * 8;
        bh[s] = ((const FragU*)p)->v;
        bl[s] = ((const FragU*)(p + 512))->v;
      }
      f32x4 acc[2];
#pragma unroll
      for (int set = 0; set < 2; ++set) acc[set] = (f32x4){0.f, 0.f, 0.f, 0.f};
#pragma unroll
      for (int s = 0; s < 4; ++s) {
#pragma unroll
        for (int set = 0; set < 2; ++set)
          acc[set] = __builtin_amdgcn_mfma_f32_16x16x32_bf16(ahi[set][s], bh[s], acc[set], 0, 0, 0);
#pragma unroll
        for (int set = 0; set < 2; ++set)
          acc[set] = __builtin_amdgcn_mfma_f32_16x16x32_bf16(ahi[set][s], bl[s], acc[set], 0, 0, 0);
#pragma unroll
        for (int set = 0; set < 2; ++set)
          acc[set] = __builtin_amdgcn_mfma_f32_16x16x32_bf16(alo[set][s], bh[s], acc[set], 0, 0, 0);
      }
      // packed top-2: key = (bits(score+en) & ~63) | (63-t)
#pragma unroll
      for (int set = 0; set < 2; ++set) {
#pragma unroll
        for (int r = 0; r < 4; ++r) {
          float sb = acc[set][r] + en;
          uint key = (__float_as_uint(sb) & 0xFFFFFFC0u) | tinv;
          uint ob = best[set * 4 + r];
          uint mn = key < ob ? key : ob;
          best[set * 4 + r] = key > ob ? key : ob;
          if (mn > best2[set * 4 + r]) best2[set * 4 + r] = mn;
        }
      }
    }
  }
  __syncthreads();  // done with staging buffers; overlay

  uint* sS = (uint*)Bsm;                     // [128][17] = 8704 B
  uint* sS2 = (uint*)((char*)Bsm + 8704);    // [128][17]
#pragma unroll
  for (int set = 0; set < 2; ++set) {
#pragma unroll
    for (int r = 0; r < 4; ++r) {
      int m = w * 32 + set * 16 + quad * 4 + r;
      sS[m * 17 + l15] = best[set * 4 + r];
      sS2[m * 17 + l15] = best2[set * 4 + r];
    }
  }
  __syncthreads();

  // per-row reduce (one row per thread, tid<128) + dist^2 from score
  if (tid < 128) {
    int m = tid;
    uint g1 = 0, g2 = 0;
    int gi = 0;
#pragma unroll 4
    for (int li = 0; li < 16; ++li) {
      uint key = sS[m * 17 + li];
      uint sb = key >> 6;
      int kk = (int)(63u - (key & 63u)) * 16 + li;
      if (sb > g1) { g2 = g1; g1 = sb; gi = kk; }
      else {
        if (sb == g1 && kk < gi) gi = kk;
        if (sb > g2) g2 = sb;
      }
      uint sb2 = sS2[m * 17 + li] >> 6;
      if (sb2 > g2) g2 = sb2;
    }
    sIdx[m] = gi;
    float s1f = __uint_as_float(g1 << 6);
    dist[m] = dist[m] - 2.0f * (s1f - SBIAS);  // ||x||^2 - 2*score
    float gap = s1f - __uint_as_float(g2 << 6);
    if (gap < MARGIN) {
      int pos = atomicAdd(lcnt, 1);
      list[pos] = m;
    }
  }
  __syncthreads();

  // ---- block-cooperative fp64 refine for flagged rows (rare) ----
  const int cnt = *lcnt;
  for (int i = 0; i < cnt; ++i) {
    const int m = list[i];
    if (tid < 128) xrowd[tid] = (double)xbase[(size_t)tid * 1024 + m];
    __syncthreads();
    double bd = 1e300;
    int bk = 0;
#pragma unroll 1
    for (int j = 0; j < 4; ++j) {
      const int k = tid * 4 + j;
      const float4* er = (const float4*)(cbn + (size_t)k * D_);
      double d = 0.0;
#pragma unroll 8
      for (int c4 = 0; c4 < 32; ++c4) {
        float4 e = er[c4];
        double d0 = xrowd[c4 * 4 + 0] - (double)e.x;
        double d1 = xrowd[c4 * 4 + 1] - (double)e.y;
        double d2 = xrowd[c4 * 4 + 2] - (double)e.z;
        double d3 = xrowd[c4 * 4 + 3] - (double)e.w;
        d = fma(d0, d0, d);
        d = fma(d1, d1, d);
        d = fma(d2, d2, d);
        d = fma(d3, d3, d);
      }
      if (d < bd) { bd = d; bk = k; }
    }
#pragma unroll
    for (int off = 32; off; off >>= 1) {
      double od = __shfl_down(bd, off, 64);
      int ok = __shfl_down(bk, off, 64);
      if (od < bd || (od == bd && ok < bk)) { bd = od; bk = ok; }
    }
    if (lane == 0) { rd[w] = bd; rk[w] = bk; }
    __syncthreads();
    if (tid == 0) {
      double gb = rd[0];
      int gk = rk[0];
      for (int t = 1; t < 4; ++t)
        if (rd[t] < gb || (rd[t] == gb && rk[t] < gk)) { gb = rd[t]; gk = rk[t]; }
      sIdx[m] = gk;
      dist[m] = (float)gb;
    }
    __syncthreads();
  }

  // ---- indices + histogram + loss ----
  if (tid < 128) {
    int bi = sIdx[tid];
    out[IDX_OFF + (b * 4 + n) * 1024 + hw0 + tid] = (float)bi;
    atomicAdd(ws + WS_CNT + n * K_ + bi, 1.0f);
  }
  float lp = (tid < 128) ? dist[tid] : 0.f;
#pragma unroll
  for (int off = 32; off; off >>= 1) lp += __shfl_down(lp, off, 64);
  if (lane == 0 && w < 2) atomicAdd(ws + WS_LOSS + n, lp);
  __syncthreads();

  // ---- quantized write via LDS-staged gather, 2 d-halves of 64 ----
  float* Qs = (float*)Bsm;  // [64 d][128 m] = 32 KB
  float* out0 = out + (size_t)((b * 4 + n) * 128) * 1024 + hw0;
#pragma unroll 1
  for (int h = 0; h < 2; ++h) {
    const int m = tid & 127, part = tid >> 7;
    const float* src = cbn + (size_t)sIdx[m] * D_ + h * 64 + part * 32;
#pragma unroll
    for (int i = 0; i < 8; ++i) {
      float4 v = ((const float4*)src)[i];
      int dl = part * 32 + i * 4;
      Qs[(dl + 0) * 128 + m] = v.x;
      Qs[(dl + 1) * 128 + m] = v.y;
      Qs[(dl + 2) * 128 + m] = v.z;
      Qs[(dl + 3) * 128 + m] = v.w;
    }
    __syncthreads();
#pragma unroll
    for (int it = 0; it < 8; ++it) {
      int e = it * 256 + tid;
      int m4 = (e & 31) * 4;
      int dl = e >> 5;
      float4 v = *(float4*)(Qs + dl * 128 + m4);
      *(float4*)(out0 + (size_t)(h * 64 + dl) * 1024 + m4) = v;
    }
    __syncthreads();
  }
}

// --- finalize: loss scale + perplexity ---
__global__ void vq_finalize(const float* __restrict__ ws, float* __restrict__ out) {
  int n = blockIdx.x;
  int t = threadIdx.x;
  const float* counts = ws + WS_CNT + n * K_;
  float s = 0.f;
  for (int k = t; k < K_; k += 256) {
    float p = counts[k] * (1.0f / 32768.0f);
    s += p * logf(p + 1e-10f);
  }
  __shared__ float red[4];
#pragma unroll
  for (int off = 32; off; off >>= 1) s += __shfl_down(s, off, 64);
  if ((t & 63) == 0) red[t >> 6] = s;
  __syncthreads();
  if (t == 0) {
    s = red[0] + red[1] + red[2] + red[3];
    out[PERP_OFF + n] = expf(-s);
    out[LOSS_OFF + n] = 1.25f * ws[WS_LOSS + n] / 4194304.0f;
  }
}

extern "C" void kernel_launch(void* const* d_in, const int* in_sizes, int n_in,
                              void* d_out, int out_size, void* d_ws, size_t ws_size,
                              hipStream_t stream) {
  const float* x = (const float*)d_in[0];
  const float* cb = (const float*)d_in[1];
  float* out = (float*)d_out;
  float* ws = (float*)d_ws;
  vq_pack<<<1281, 256, 0, stream>>>(cb, ws);
  vq_main<<<1024, 256, 0, stream>>>(x, cb, ws, out);
  vq_finalize<<<4, 256, 0, stream>>>(ws, out);
}